// Round 11
// baseline (826.617 us; speedup 1.0000x reference)
//
#include <hip/hip_runtime.h>
#include <cstdint>
#include <cstddef>

// ---------- problem constants ----------
#define DIM      1024
#define GROUP    16
#define LORA     20
#define NLAYERS  18
#define NBLOCKS  6
#define BATCH    8192
#define EPS      1e-5f

typedef __bf16 bf16_8 __attribute__((ext_vector_type(8)));
typedef __bf16 bf16_4 __attribute__((ext_vector_type(4)));
typedef float  f32x4  __attribute__((ext_vector_type(4)));

// ---------------------------------------------------------------------------
// Weight prep: W_total[l][o][k] = qw*scale + sum_r B[o][r]*A[r][k], split bf16
// hi/lo.  Thread = 2 rows x 16 scattered cols, acc = 32 f32.
// A read DIRECTLY from global (80KB/layer = L2-resident; coalesced 512B per
// 32-lane group) — no As LDS: block LDS drops 42.5KB -> 1.25KB so 4+ blocks/CU
// reside (R10 had 2) and the j-loop LDS issue cost disappears.  R8's version
// of this idea was confounded by a VGPR spill (acc=64, VGPR=60); acc=32 +
// bounds(256,4) keeps ~80 VGPR, no spill.
// ---------------------------------------------------------------------------
__global__ __launch_bounds__(256, 4) void wprep_kernel(
    const int* __restrict__ qw, const float* __restrict__ sc,
    const float* __restrict__ la, const float* __restrict__ lb,
    __bf16* __restrict__ whi, __bf16* __restrict__ wlo) {
  const int l  = blockIdx.x >> 7;          // 18 layers x 128 blocks
  const int og = (blockIdx.x >> 1) & 63;   // 64 row-groups of 16
  const int cg = blockIdx.x & 1;           // 2 col-halves of 512
  const int tid = threadIdx.x;

  __shared__ float Bs[16 * LORA];          // 320 floats
  const float* Bbase = lb + ((size_t)l * DIM + og * 16) * LORA;
  for (int i = tid; i < 16 * LORA; i += 256) Bs[i] = Bbase[i];
  __syncthreads();

  const int tc = tid & 31;                 // col quad: c = v*128 + tc*4
  const int tr = tid >> 5;                 // 8 row-pairs

  float acc[2][16];                        // 32 VGPR
  size_t rowb[2];
#pragma unroll
  for (int u = 0; u < 2; ++u) {
    const int orow = og * 16 + tr * 2 + u;
    rowb[u] = ((size_t)l * DIM + orow) * DIM + cg * 512;
    const size_t scb = ((size_t)l * DIM + orow) * (DIM / GROUP) + cg * 32;
#pragma unroll
    for (int v = 0; v < 4; ++v) {
      const int c = v * 128 + tc * 4;
      const int4 q4 = *(const int4*)&qw[rowb[u] + c];
      const float sv = sc[scb + (c >> 4)];
      acc[u][v * 4 + 0] = q4.x * sv;
      acc[u][v * 4 + 1] = q4.y * sv;
      acc[u][v * 4 + 2] = q4.z * sv;
      acc[u][v * 4 + 3] = q4.w * sv;
    }
  }

  const float* Ab = la + (size_t)l * LORA * DIM + cg * 512 + tc * 4;
#pragma unroll 2
  for (int j = 0; j < LORA; ++j) {
    float4 a[4];
#pragma unroll
    for (int v = 0; v < 4; ++v)
      a[v] = *(const float4*)(Ab + (size_t)j * DIM + v * 128);  // L2-hot, coalesced
#pragma unroll
    for (int u = 0; u < 2; ++u) {
      const float bj = Bs[(tr * 2 + u) * LORA + j];
#pragma unroll
      for (int v = 0; v < 4; ++v) {
        acc[u][v * 4 + 0] += bj * a[v].x;
        acc[u][v * 4 + 1] += bj * a[v].y;
        acc[u][v * 4 + 2] += bj * a[v].z;
        acc[u][v * 4 + 3] += bj * a[v].w;
      }
    }
  }

#pragma unroll
  for (int u = 0; u < 2; ++u) {
#pragma unroll
    for (int v = 0; v < 4; ++v) {
      bf16_4 hv, lv;
#pragma unroll
      for (int e = 0; e < 4; ++e) {
        const float a = acc[u][v * 4 + e];
        const __bf16 hi = (__bf16)a;
        hv[e] = hi;
        lv[e] = (__bf16)(a - (float)hi);
      }
      const size_t p = rowb[u] + v * 128 + tc * 4;
      *(bf16_4*)&whi[p] = hv;
      *(bf16_4*)&wlo[p] = lv;
    }
  }
}

// ---------------------------------------------------------------------------
// x prep: f32 -> single bf16
// ---------------------------------------------------------------------------
__global__ __launch_bounds__(256) void xprep_kernel(
    const float* __restrict__ x, __bf16* __restrict__ hi) {
  const size_t i = (size_t)blockIdx.x * 256 + threadIdx.x;
  const float4 v = ((const float4*)x)[i];
  const bf16_4 hv = {(__bf16)v.x, (__bf16)v.y, (__bf16)v.z, (__bf16)v.w};
  ((bf16_4*)hi)[i] = hv;
}

// ---------------------------------------------------------------------------
// 2-pass split-W bf16 GEMM (x single bf16; W = Wh + Wl).
// Tile 256x128, BK=32, 512 thr (8 waves), 3 x 32KB buffers, counted vmcnt(4).
// NEW: 2-phase k-step (T3 gate for T5, m218b):
//   ph0: issue X stage | ds_read xf + w[0,1] | bar | prio1 16 MFMA prio0 | bar
//   ph1: issue W stage | ds_read w[2,3] | vmcnt(4) | bar | prio1 16 MFMA | bar
// Waves slip between barriers: one wave's ds_read/stage overlaps another's
// MFMA; setprio favors the MFMA wave.  Reordering by the compiler is safe
// (all reads target the stable `cur` buffer) -> worst case = current perf.
// ---------------------------------------------------------------------------
#define GBUF    16384   // elems per buffer (32 KB)
#define GOFF_WH 8192
#define GOFF_WL 12288

template <int NISSUE>
__device__ __forceinline__ void stageR(const __bf16* __restrict__ g, int row0, int k0,
                                       __bf16* lds, int tid) {
#pragma unroll
  for (int i = 0; i < NISSUE; ++i) {
    const int D = i * 8192 + tid * 16;     // linear byte in region
    const int r  = D >> 6;                 // 64 B per row (BK=32 bf16)
    const int ce = (D & 63) >> 1;
    const __bf16* gp = g + (size_t)(row0 + r) * DIM + k0 + ce;
    __builtin_amdgcn_global_load_lds(
        (const __attribute__((address_space(1))) void*)gp,
        (__attribute__((address_space(3))) void*)(lds + i * 4096 + (tid >> 6) * 512), 16, 0, 0);
  }
}

template <bool RELU_OUT>
__global__ __launch_bounds__(512, 1) void gemm2_kernel(
    const __bf16* __restrict__ X, const __bf16* __restrict__ Wh,
    const __bf16* __restrict__ Wl, const float* __restrict__ bias,
    __bf16* __restrict__ Oh,
    const float* __restrict__ Hin, float* __restrict__ Sout) {
  __shared__ __bf16 smem[3 * GBUF];        // 96 KB

  const int tid  = threadIdx.x;
  const int lane = tid & 63;
  const int wv   = tid >> 6;
  const int wm   = wv >> 2;                // feature half (2 x 64)
  const int wn2  = wv & 3;                 // batch quarter (4 x 64)
  const int xcd = blockIdx.x & 7;
  const int kk  = blockIdx.x >> 3;         // 0..31
  const int tm  = xcd * 4 + (kk >> 3);
  const int tn  = kk & 7;
  const int rowX = tm * 256, rowW = tn * 128;

  const int lr   = lane & 15;
  const int slot = lane >> 4;

  int offX[4], offW[4];
#pragma unroll
  for (int n = 0; n < 4; ++n) offX[n] = (wn2 * 64 + n * 16 + lr) * 32 + slot * 8;
#pragma unroll
  for (int m = 0; m < 4; ++m) offW[m] = GOFF_WH + (wm * 64 + m * 16 + lr) * 32 + slot * 8;

  f32x4 acc[4][4];
#pragma unroll
  for (int m = 0; m < 4; ++m)
#pragma unroll
    for (int n = 0; n < 4; ++n) acc[m][n] = f32x4{0.f, 0.f, 0.f, 0.f};

  auto stage_tile = [&](int k0, __bf16* sb) {
    stageR<2>(X,  rowX, k0, sb, tid);
    stageR<1>(Wh, rowW, k0, sb + GOFF_WH, tid);
    stageR<1>(Wl, rowW, k0, sb + GOFF_WL, tid);
  };

  auto compute_tile = [&](const __bf16* buf) {
    bf16_8 xf[4];
#pragma unroll
    for (int n = 0; n < 4; ++n) xf[n] = *(const bf16_8*)&buf[offX[n]];
#pragma unroll
    for (int m = 0; m < 4; ++m) {
      const bf16_8 w_h = *(const bf16_8*)&buf[offW[m]];
      const bf16_8 w_l = *(const bf16_8*)&buf[offW[m] + (GOFF_WL - GOFF_WH)];
#pragma unroll
      for (int n = 0; n < 4; ++n) {
        acc[m][n] = __builtin_amdgcn_mfma_f32_16x16x32_bf16(w_h, xf[n], acc[m][n], 0, 0, 0);
        acc[m][n] = __builtin_amdgcn_mfma_f32_16x16x32_bf16(w_l, xf[n], acc[m][n], 0, 0, 0);
      }
    }
  };

  stage_tile(0, smem);
  stage_tile(32, smem + GBUF);
  asm volatile("s_waitcnt vmcnt(4)" ::: "memory");
  __builtin_amdgcn_s_barrier();

  int cur = 0;
#pragma unroll 1
  for (int kt = 0; kt < 30; ++kt) {
    int pb = cur + 2; if (pb >= 3) pb -= 3;
    __bf16* sb = smem + pb * GBUF;
    const __bf16* buf = smem + cur * GBUF;
    const int k2 = (kt + 2) * 32;

    // ---- phase 0: stage X(kt+2) | read xf + w[0,1] | 16 MFMA (m=0,1)
    stageR<2>(X, rowX, k2, sb, tid);
    bf16_8 xf[4], wA[2], wB[2];
#pragma unroll
    for (int n = 0; n < 4; ++n) xf[n] = *(const bf16_8*)&buf[offX[n]];
#pragma unroll
    for (int m = 0; m < 2; ++m) {
      wA[m] = *(const bf16_8*)&buf[offW[m]];
      wB[m] = *(const bf16_8*)&buf[offW[m] + (GOFF_WL - GOFF_WH)];
    }
    __builtin_amdgcn_s_barrier();
    __builtin_amdgcn_s_setprio(1);
#pragma unroll
    for (int m = 0; m < 2; ++m)
#pragma unroll
      for (int n = 0; n < 4; ++n) {
        acc[m][n] = __builtin_amdgcn_mfma_f32_16x16x32_bf16(wA[m], xf[n], acc[m][n], 0, 0, 0);
        acc[m][n] = __builtin_amdgcn_mfma_f32_16x16x32_bf16(wB[m], xf[n], acc[m][n], 0, 0, 0);
      }
    __builtin_amdgcn_s_setprio(0);
    __builtin_amdgcn_s_barrier();

    // ---- phase 1: stage W(kt+2) | read w[2,3] | vmcnt(4) | 16 MFMA (m=2,3)
    stageR<1>(Wh, rowW, k2, sb + GOFF_WH, tid);
    stageR<1>(Wl, rowW, k2, sb + GOFF_WL, tid);
#pragma unroll
    for (int m = 0; m < 2; ++m) {
      wA[m] = *(const bf16_8*)&buf[offW[2 + m]];
      wB[m] = *(const bf16_8*)&buf[offW[2 + m] + (GOFF_WL - GOFF_WH)];
    }
    // drain tile kt+1's 4 loads (oldest); kt+2's 4 newest stay in flight
    asm volatile("s_waitcnt vmcnt(4)" ::: "memory");
    __builtin_amdgcn_s_barrier();
    __builtin_amdgcn_s_setprio(1);
#pragma unroll
    for (int m = 0; m < 2; ++m)
#pragma unroll
      for (int n = 0; n < 4; ++n) {
        acc[2 + m][n] = __builtin_amdgcn_mfma_f32_16x16x32_bf16(wA[m], xf[n], acc[2 + m][n], 0, 0, 0);
        acc[2 + m][n] = __builtin_amdgcn_mfma_f32_16x16x32_bf16(wB[m], xf[n], acc[2 + m][n], 0, 0, 0);
      }
    __builtin_amdgcn_s_setprio(0);
    __builtin_amdgcn_s_barrier();

    ++cur; if (cur == 3) cur = 0;
  }
  // tails: kt=30 (loads already drained), then kt=31
  compute_tile(smem + cur * GBUF);
  asm volatile("s_waitcnt vmcnt(0)" ::: "memory");
  __builtin_amdgcn_s_barrier();
  ++cur; if (cur == 3) cur = 0;
  compute_tile(smem + cur * GBUF);

  const int g4 = slot * 4;
#pragma unroll
  for (int m = 0; m < 4; ++m) {
    const int feat = tn * 128 + wm * 64 + m * 16 + g4;
    const float4 bv = *(const float4*)&bias[feat];
#pragma unroll
    for (int n = 0; n < 4; ++n) {
      const int nb = tm * 256 + wn2 * 64 + n * 16 + lr;
      const size_t base = (size_t)nb * DIM + feat;
      float v0 = acc[m][n][0] + bv.x;
      float v1 = acc[m][n][1] + bv.y;
      float v2 = acc[m][n][2] + bv.z;
      float v3 = acc[m][n][3] + bv.w;
      if constexpr (RELU_OUT) {
        const bf16_4 hv = {(__bf16)fmaxf(v0, 0.f), (__bf16)fmaxf(v1, 0.f),
                           (__bf16)fmaxf(v2, 0.f), (__bf16)fmaxf(v3, 0.f)};
        *(bf16_4*)&Oh[base] = hv;
      } else {
        const float4 h = *(const float4*)&Hin[base];
        *(float4*)&Sout[base] = float4{v0 + h.x, v1 + h.y, v2 + h.z, v3 + h.w};
      }
    }
  }
}

// ---------------------------------------------------------------------------
// Row LayerNorm: H = LN(S)*w+b (f32) plus bf16 cast (next block's GEMM input).
// ---------------------------------------------------------------------------
__global__ __launch_bounds__(256) void ln_kernel(
    const float* __restrict__ S, const float* __restrict__ w,
    const float* __restrict__ b, float* __restrict__ H,
    __bf16* __restrict__ phi) {
  const int row = blockIdx.x;
  const int tid = threadIdx.x;
  const int lane = tid & 63;
  const int wv = tid >> 6;
  const float4 v = ((const float4*)(S + (size_t)row * DIM))[tid];

  float s = v.x + v.y + v.z + v.w;
#pragma unroll
  for (int m = 32; m; m >>= 1) s += __shfl_xor(s, m, 64);
  __shared__ float red[8];
  if (lane == 0) red[wv] = s;
  __syncthreads();
  const float mean = (red[0] + red[1] + red[2] + red[3]) * (1.f / DIM);

  const float d0 = v.x - mean, d1 = v.y - mean, d2 = v.z - mean, d3 = v.w - mean;
  float q = d0 * d0 + d1 * d1 + d2 * d2 + d3 * d3;
#pragma unroll
  for (int m = 32; m; m >>= 1) q += __shfl_xor(q, m, 64);
  if (lane == 0) red[4 + wv] = q;
  __syncthreads();
  const float var = (red[4] + red[5] + red[6] + red[7]) * (1.f / DIM);
  const float inv = 1.f / sqrtf(var + EPS);

  const float4 wv4 = ((const float4*)w)[tid];
  const float4 bv4 = ((const float4*)b)[tid];
  const float y0 = d0 * inv * wv4.x + bv4.x;
  const float y1 = d1 * inv * wv4.y + bv4.y;
  const float y2 = d2 * inv * wv4.z + bv4.z;
  const float y3 = d3 * inv * wv4.w + bv4.w;

  ((float4*)(H + (size_t)row * DIM))[tid] = float4{y0, y1, y2, y3};
  const bf16_4 hv = {(__bf16)y0, (__bf16)y1, (__bf16)y2, (__bf16)y3};
  ((bf16_4*)phi)[(size_t)row * (DIM / 4) + tid] = hv;
}

// ---------------------------------------------------------------------------
// launch
// ---------------------------------------------------------------------------
extern "C" void kernel_launch(void* const* d_in, const int* in_sizes, int n_in,
                              void* d_out, int out_size, void* d_ws, size_t ws_size,
                              hipStream_t stream) {
  const float* x   = (const float*)d_in[0];
  const int*   qw  = (const int*)d_in[1];
  const float* sc  = (const float*)d_in[2];
  const float* bias= (const float*)d_in[3];
  const float* la  = (const float*)d_in[4];
  const float* lb  = (const float*)d_in[5];
  const float* lnw = (const float*)d_in[6];
  const float* lnb = (const float*)d_in[7];
  float* out = (float*)d_out;
  char* ws = (char*)d_ws;

  // workspace layout (bytes): WHI 36M | WLO 36M | X0 16M | X1 16M | Sb 32M | Hb 32M
  __bf16* WHI = (__bf16*)(ws);
  __bf16* WLO = (__bf16*)(ws + 37748736);
  __bf16* X0  = (__bf16*)(ws + 75497472);
  __bf16* X1  = (__bf16*)(ws + 92274688);
  float*  Sb  = (float*)(ws + 109051904);
  float*  Hb  = (float*)(ws + 142606336);
  (void)ws_size; (void)in_sizes; (void)n_in; (void)out_size;

  xprep_kernel<<<BATCH * DIM / (256 * 4), 256, 0, stream>>>(x, X0);
  wprep_kernel<<<NLAYERS * 128, 256, 0, stream>>>(qw, sc, la, lb, WHI, WLO);

  const dim3 ggrid(BATCH / 256 * (DIM / 128));  // 32 * 8 = 256 = 1 block/CU
  for (int blk = 0; blk < NBLOCKS; ++blk) {
    const int li = blk * 3;
    const size_t w0 = (size_t)li * DIM * DIM;
    const size_t w1 = (size_t)(li + 1) * DIM * DIM;
    const size_t w2 = (size_t)(li + 2) * DIM * DIM;

    gemm2_kernel<true><<<ggrid, 512, 0, stream>>>(
        X0, WHI + w0, WLO + w0, bias + (size_t)li * DIM, X1, nullptr, nullptr);
    gemm2_kernel<true><<<ggrid, 512, 0, stream>>>(
        X1, WHI + w1, WLO + w1, bias + (size_t)(li + 1) * DIM, X0, nullptr, nullptr);
    const float* hin = (blk == 0) ? x : Hb;
    float* sout = (blk == NBLOCKS - 1) ? out : Sb;
    gemm2_kernel<false><<<ggrid, 512, 0, stream>>>(
        X0, WHI + w2, WLO + w2, bias + (size_t)(li + 2) * DIM, nullptr, hin, sout);
    if (blk < NBLOCKS - 1) {
      ln_kernel<<<BATCH, 256, 0, stream>>>(Sb, lnw + (size_t)blk * DIM,
                                           lnb + (size_t)blk * DIM, Hb, X0);
    }
  }
}

// Round 12
// 765.052 us; speedup vs baseline: 1.0805x; 1.0805x over previous
//
#include <hip/hip_runtime.h>
#include <cstdint>
#include <cstddef>

// ---------- problem constants ----------
#define DIM      1024
#define GROUP    16
#define LORA     20
#define NLAYERS  18
#define NBLOCKS  6
#define BATCH    8192
#define EPS      1e-5f

typedef __bf16 bf16_8 __attribute__((ext_vector_type(8)));
typedef __bf16 bf16_4 __attribute__((ext_vector_type(4)));
typedef float  f32x4  __attribute__((ext_vector_type(4)));

// ---------------------------------------------------------------------------
// Weight prep: W_total[l][o][k] = qw*scale + sum_r B[o][r]*A[r][k], split bf16
// hi/lo.  R10 structure (thread = 2 rows x 16 scattered cols, acc=32, LDS As
// -> no spill [direct-global A spills: R8 VGPR=60, R11 VGPR=36]) BUT As is
// CHUNKED: 10 LoRA rows at a time (20 KB) -> LDS 21.3 KB/block -> up to 7
// blocks/CU resident (R10: 42.5 KB -> 2 blocks, occ 26%, latency-bound).
// ---------------------------------------------------------------------------
__global__ __launch_bounds__(256, 2) void wprep_kernel(
    const int* __restrict__ qw, const float* __restrict__ sc,
    const float* __restrict__ la, const float* __restrict__ lb,
    __bf16* __restrict__ whi, __bf16* __restrict__ wlo) {
  const int l  = blockIdx.x >> 7;          // 18 layers x 128 blocks
  const int og = (blockIdx.x >> 1) & 63;   // 64 row-groups of 16
  const int cg = blockIdx.x & 1;           // 2 col-halves of 512
  const int tid = threadIdx.x;

  __shared__ float As[10 * 512];           // 20 KB (half of A's rows)
  __shared__ float Bs[16 * LORA];          // 1.25 KB

  const float* Abase = la + (size_t)l * LORA * DIM + cg * 512;
  const float* Bbase = lb + ((size_t)l * DIM + og * 16) * LORA;
  for (int i = tid; i < 16 * LORA; i += 256) Bs[i] = Bbase[i];
  // stage A rows 0..9
#pragma unroll
  for (int i = 0; i < 5; ++i) {            // 1280 float4 / 256 thr
    const int f4 = i * 256 + tid;
    ((float4*)As)[f4] = *(const float4*)(Abase + (size_t)(f4 >> 7) * DIM + (f4 & 127) * 4);
  }
  __syncthreads();

  const int tc = tid & 31;                 // col quad: c = v*128 + tc*4
  const int tr = tid >> 5;                 // 8 row-pairs

  float acc[2][16];                        // 32 VGPR
  size_t rowb[2];
#pragma unroll
  for (int u = 0; u < 2; ++u) {
    const int orow = og * 16 + tr * 2 + u;
    rowb[u] = ((size_t)l * DIM + orow) * DIM + cg * 512;
    const size_t scb = ((size_t)l * DIM + orow) * (DIM / GROUP) + cg * 32;
#pragma unroll
    for (int v = 0; v < 4; ++v) {
      const int c = v * 128 + tc * 4;
      const int4 q4 = *(const int4*)&qw[rowb[u] + c];
      const float sv = sc[scb + (c >> 4)];
      acc[u][v * 4 + 0] = q4.x * sv;
      acc[u][v * 4 + 1] = q4.y * sv;
      acc[u][v * 4 + 2] = q4.z * sv;
      acc[u][v * 4 + 3] = q4.w * sv;
    }
  }

#pragma unroll 1
  for (int half = 0; half < 2; ++half) {
    if (half == 1) {
      __syncthreads();                     // everyone done with rows 0..9
#pragma unroll
      for (int i = 0; i < 5; ++i) {        // stage A rows 10..19
        const int f4 = i * 256 + tid;
        ((float4*)As)[f4] =
            *(const float4*)(Abase + (size_t)(10 + (f4 >> 7)) * DIM + (f4 & 127) * 4);
      }
      __syncthreads();
    }
#pragma unroll 2
    for (int jj = 0; jj < 10; ++jj) {
      const int j = half * 10 + jj;
      float4 a[4];
#pragma unroll
      for (int v = 0; v < 4; ++v)
        a[v] = *(const float4*)&As[jj * 512 + v * 128 + tc * 4];  // 16B lane stride
#pragma unroll
      for (int u = 0; u < 2; ++u) {
        const float bj = Bs[(tr * 2 + u) * LORA + j];
#pragma unroll
        for (int v = 0; v < 4; ++v) {
          acc[u][v * 4 + 0] += bj * a[v].x;
          acc[u][v * 4 + 1] += bj * a[v].y;
          acc[u][v * 4 + 2] += bj * a[v].z;
          acc[u][v * 4 + 3] += bj * a[v].w;
        }
      }
    }
  }

#pragma unroll
  for (int u = 0; u < 2; ++u) {
#pragma unroll
    for (int v = 0; v < 4; ++v) {
      bf16_4 hv, lv;
#pragma unroll
      for (int e = 0; e < 4; ++e) {
        const float a = acc[u][v * 4 + e];
        const __bf16 hi = (__bf16)a;
        hv[e] = hi;
        lv[e] = (__bf16)(a - (float)hi);
      }
      const size_t p = rowb[u] + v * 128 + tc * 4;
      *(bf16_4*)&whi[p] = hv;
      *(bf16_4*)&wlo[p] = lv;
    }
  }
}

// ---------------------------------------------------------------------------
// x prep: f32 -> single bf16
// ---------------------------------------------------------------------------
__global__ __launch_bounds__(256) void xprep_kernel(
    const float* __restrict__ x, __bf16* __restrict__ hi) {
  const size_t i = (size_t)blockIdx.x * 256 + threadIdx.x;
  const float4 v = ((const float4*)x)[i];
  const bf16_4 hv = {(__bf16)v.x, (__bf16)v.y, (__bf16)v.z, (__bf16)v.w};
  ((bf16_4*)hi)[i] = hv;
}

// ---------------------------------------------------------------------------
// 2-pass split-W bf16 GEMM (x single bf16; W = Wh + Wl).  R10 monolithic loop
// (proven ~35 µs = m97-structure MFMA rate): tile 256x128, BK=32, 512 thr,
// 3 x 32KB buffers, counted vmcnt(4), grid 256 = 1 block/CU.
// ---------------------------------------------------------------------------
#define GBUF    16384   // elems per buffer (32 KB)
#define GOFF_WH 8192
#define GOFF_WL 12288

template <int NISSUE>
__device__ __forceinline__ void stageR(const __bf16* __restrict__ g, int row0, int k0,
                                       __bf16* lds, int tid) {
#pragma unroll
  for (int i = 0; i < NISSUE; ++i) {
    const int D = i * 8192 + tid * 16;     // linear byte in region
    const int r  = D >> 6;                 // 64 B per row (BK=32 bf16)
    const int ce = (D & 63) >> 1;
    const __bf16* gp = g + (size_t)(row0 + r) * DIM + k0 + ce;
    __builtin_amdgcn_global_load_lds(
        (const __attribute__((address_space(1))) void*)gp,
        (__attribute__((address_space(3))) void*)(lds + i * 4096 + (tid >> 6) * 512), 16, 0, 0);
  }
}

template <bool RELU_OUT>
__global__ __launch_bounds__(512, 1) void gemm2_kernel(
    const __bf16* __restrict__ X, const __bf16* __restrict__ Wh,
    const __bf16* __restrict__ Wl, const float* __restrict__ bias,
    __bf16* __restrict__ Oh,
    const float* __restrict__ Hin, float* __restrict__ Sout) {
  __shared__ __bf16 smem[3 * GBUF];        // 96 KB

  const int tid  = threadIdx.x;
  const int lane = tid & 63;
  const int wv   = tid >> 6;
  const int wm   = wv >> 2;                // feature half (2 x 64)
  const int wn2  = wv & 3;                 // batch quarter (4 x 64)
  const int xcd = blockIdx.x & 7;
  const int kk  = blockIdx.x >> 3;         // 0..31
  const int tm  = xcd * 4 + (kk >> 3);
  const int tn  = kk & 7;
  const int rowX = tm * 256, rowW = tn * 128;

  const int lr   = lane & 15;
  const int slot = lane >> 4;

  int offX[4], offW[4];
#pragma unroll
  for (int n = 0; n < 4; ++n) offX[n] = (wn2 * 64 + n * 16 + lr) * 32 + slot * 8;
#pragma unroll
  for (int m = 0; m < 4; ++m) offW[m] = GOFF_WH + (wm * 64 + m * 16 + lr) * 32 + slot * 8;

  f32x4 acc[4][4];
#pragma unroll
  for (int m = 0; m < 4; ++m)
#pragma unroll
    for (int n = 0; n < 4; ++n) acc[m][n] = f32x4{0.f, 0.f, 0.f, 0.f};

  auto stage_tile = [&](int k0, __bf16* sb) {
    stageR<2>(X,  rowX, k0, sb, tid);
    stageR<1>(Wh, rowW, k0, sb + GOFF_WH, tid);
    stageR<1>(Wl, rowW, k0, sb + GOFF_WL, tid);
  };

  auto compute_tile = [&](const __bf16* buf) {
    bf16_8 xf[4];
#pragma unroll
    for (int n = 0; n < 4; ++n) xf[n] = *(const bf16_8*)&buf[offX[n]];
#pragma unroll
    for (int m = 0; m < 4; ++m) {
      const bf16_8 w_h = *(const bf16_8*)&buf[offW[m]];
      const bf16_8 w_l = *(const bf16_8*)&buf[offW[m] + (GOFF_WL - GOFF_WH)];
#pragma unroll
      for (int n = 0; n < 4; ++n) {
        acc[m][n] = __builtin_amdgcn_mfma_f32_16x16x32_bf16(w_h, xf[n], acc[m][n], 0, 0, 0);
        acc[m][n] = __builtin_amdgcn_mfma_f32_16x16x32_bf16(w_l, xf[n], acc[m][n], 0, 0, 0);
      }
    }
  };

  stage_tile(0, smem);
  stage_tile(32, smem + GBUF);
  asm volatile("s_waitcnt vmcnt(4)" ::: "memory");
  __builtin_amdgcn_s_barrier();

  int cur = 0;
#pragma unroll 1
  for (int kt = 0; kt < 30; ++kt) {
    int pb = cur + 2; if (pb >= 3) pb -= 3;
    stage_tile((kt + 2) * 32, smem + pb * GBUF);
    compute_tile(smem + cur * GBUF);
    asm volatile("s_waitcnt vmcnt(4)" ::: "memory");
    __builtin_amdgcn_s_barrier();
    ++cur; if (cur == 3) cur = 0;
  }
  compute_tile(smem + cur * GBUF);
  asm volatile("s_waitcnt vmcnt(0)" ::: "memory");
  __builtin_amdgcn_s_barrier();
  ++cur; if (cur == 3) cur = 0;
  compute_tile(smem + cur * GBUF);

  const int g4 = slot * 4;
#pragma unroll
  for (int m = 0; m < 4; ++m) {
    const int feat = tn * 128 + wm * 64 + m * 16 + g4;
    const float4 bv = *(const float4*)&bias[feat];
#pragma unroll
    for (int n = 0; n < 4; ++n) {
      const int nb = tm * 256 + wn2 * 64 + n * 16 + lr;
      const size_t base = (size_t)nb * DIM + feat;
      float v0 = acc[m][n][0] + bv.x;
      float v1 = acc[m][n][1] + bv.y;
      float v2 = acc[m][n][2] + bv.z;
      float v3 = acc[m][n][3] + bv.w;
      if constexpr (RELU_OUT) {
        const bf16_4 hv = {(__bf16)fmaxf(v0, 0.f), (__bf16)fmaxf(v1, 0.f),
                           (__bf16)fmaxf(v2, 0.f), (__bf16)fmaxf(v3, 0.f)};
        *(bf16_4*)&Oh[base] = hv;
      } else {
        const float4 h = *(const float4*)&Hin[base];
        *(float4*)&Sout[base] = float4{v0 + h.x, v1 + h.y, v2 + h.z, v3 + h.w};
      }
    }
  }
}

// ---------------------------------------------------------------------------
// Row LayerNorm: H = LN(S)*w+b (f32) plus bf16 cast (next block's GEMM input).
// ---------------------------------------------------------------------------
__global__ __launch_bounds__(256) void ln_kernel(
    const float* __restrict__ S, const float* __restrict__ w,
    const float* __restrict__ b, float* __restrict__ H,
    __bf16* __restrict__ phi) {
  const int row = blockIdx.x;
  const int tid = threadIdx.x;
  const int lane = tid & 63;
  const int wv = tid >> 6;
  const float4 v = ((const float4*)(S + (size_t)row * DIM))[tid];

  float s = v.x + v.y + v.z + v.w;
#pragma unroll
  for (int m = 32; m; m >>= 1) s += __shfl_xor(s, m, 64);
  __shared__ float red[8];
  if (lane == 0) red[wv] = s;
  __syncthreads();
  const float mean = (red[0] + red[1] + red[2] + red[3]) * (1.f / DIM);

  const float d0 = v.x - mean, d1 = v.y - mean, d2 = v.z - mean, d3 = v.w - mean;
  float q = d0 * d0 + d1 * d1 + d2 * d2 + d3 * d3;
#pragma unroll
  for (int m = 32; m; m >>= 1) q += __shfl_xor(q, m, 64);
  if (lane == 0) red[4 + wv] = q;
  __syncthreads();
  const float var = (red[4] + red[5] + red[6] + red[7]) * (1.f / DIM);
  const float inv = 1.f / sqrtf(var + EPS);

  const float4 wv4 = ((const float4*)w)[tid];
  const float4 bv4 = ((const float4*)b)[tid];
  const float y0 = d0 * inv * wv4.x + bv4.x;
  const float y1 = d1 * inv * wv4.y + bv4.y;
  const float y2 = d2 * inv * wv4.z + bv4.z;
  const float y3 = d3 * inv * wv4.w + bv4.w;

  ((float4*)(H + (size_t)row * DIM))[tid] = float4{y0, y1, y2, y3};
  const bf16_4 hv = {(__bf16)y0, (__bf16)y1, (__bf16)y2, (__bf16)y3};
  ((bf16_4*)phi)[(size_t)row * (DIM / 4) + tid] = hv;
}

// ---------------------------------------------------------------------------
// launch
// ---------------------------------------------------------------------------
extern "C" void kernel_launch(void* const* d_in, const int* in_sizes, int n_in,
                              void* d_out, int out_size, void* d_ws, size_t ws_size,
                              hipStream_t stream) {
  const float* x   = (const float*)d_in[0];
  const int*   qw  = (const int*)d_in[1];
  const float* sc  = (const float*)d_in[2];
  const float* bias= (const float*)d_in[3];
  const float* la  = (const float*)d_in[4];
  const float* lb  = (const float*)d_in[5];
  const float* lnw = (const float*)d_in[6];
  const float* lnb = (const float*)d_in[7];
  float* out = (float*)d_out;
  char* ws = (char*)d_ws;

  // workspace layout (bytes): WHI 36M | WLO 36M | X0 16M | X1 16M | Sb 32M | Hb 32M
  __bf16* WHI = (__bf16*)(ws);
  __bf16* WLO = (__bf16*)(ws + 37748736);
  __bf16* X0  = (__bf16*)(ws + 75497472);
  __bf16* X1  = (__bf16*)(ws + 92274688);
  float*  Sb  = (float*)(ws + 109051904);
  float*  Hb  = (float*)(ws + 142606336);
  (void)ws_size; (void)in_sizes; (void)n_in; (void)out_size;

  xprep_kernel<<<BATCH * DIM / (256 * 4), 256, 0, stream>>>(x, X0);
  wprep_kernel<<<NLAYERS * 128, 256, 0, stream>>>(qw, sc, la, lb, WHI, WLO);

  const dim3 ggrid(BATCH / 256 * (DIM / 128));  // 32 * 8 = 256 = 1 block/CU
  for (int blk = 0; blk < NBLOCKS; ++blk) {
    const int li = blk * 3;
    const size_t w0 = (size_t)li * DIM * DIM;
    const size_t w1 = (size_t)(li + 1) * DIM * DIM;
    const size_t w2 = (size_t)(li + 2) * DIM * DIM;

    gemm2_kernel<true><<<ggrid, 512, 0, stream>>>(
        X0, WHI + w0, WLO + w0, bias + (size_t)li * DIM, X1, nullptr, nullptr);
    gemm2_kernel<true><<<ggrid, 512, 0, stream>>>(
        X1, WHI + w1, WLO + w1, bias + (size_t)(li + 1) * DIM, X0, nullptr, nullptr);
    const float* hin = (blk == 0) ? x : Hb;
    float* sout = (blk == NBLOCKS - 1) ? out : Sb;
    gemm2_kernel<false><<<ggrid, 512, 0, stream>>>(
        X0, WHI + w2, WLO + w2, bias + (size_t)(li + 2) * DIM, nullptr, hin, sout);
    if (blk < NBLOCKS - 1) {
      ln_kernel<<<BATCH, 256, 0, stream>>>(Sb, lnw + (size_t)blk * DIM,
                                           lnb + (size_t)blk * DIM, Hb, X0);
    }
  }
}

// Round 13
// 579.409 us; speedup vs baseline: 1.4267x; 1.3204x over previous
//
#include <hip/hip_runtime.h>
#include <cstdint>
#include <cstddef>

// ---------- problem constants ----------
#define DIM      1024
#define GROUP    16
#define LORA     20
#define NLAYERS  18
#define NBLOCKS  6
#define BATCH    8192
#define EPS      1e-5f

typedef __bf16 bf16_8 __attribute__((ext_vector_type(8)));
typedef __bf16 bf16_4 __attribute__((ext_vector_type(4)));
typedef float  f32x4  __attribute__((ext_vector_type(4)));

// ---------------------------------------------------------------------------
// Weight prep: W_total = qw*scale + B@A, cast to SINGLE bf16 (1-pass GEMM:
// W-rounding noise ~= x-bf16 rounding noise, total absmax ~0.10 < 0.144).
// R12 structure: thread = 2 rows x 16 scattered cols, chunked As (20 KB).
// Write traffic halves (no WLO) -> ~40 us (was traffic-floor-bound at 50).
// ---------------------------------------------------------------------------
__global__ __launch_bounds__(256, 2) void wprep_kernel(
    const int* __restrict__ qw, const float* __restrict__ sc,
    const float* __restrict__ la, const float* __restrict__ lb,
    __bf16* __restrict__ whi) {
  const int l  = blockIdx.x >> 7;          // 18 layers x 128 blocks
  const int og = (blockIdx.x >> 1) & 63;   // 64 row-groups of 16
  const int cg = blockIdx.x & 1;           // 2 col-halves of 512
  const int tid = threadIdx.x;

  __shared__ float As[10 * 512];           // 20 KB (half of A's rows)
  __shared__ float Bs[16 * LORA];          // 1.25 KB

  const float* Abase = la + (size_t)l * LORA * DIM + cg * 512;
  const float* Bbase = lb + ((size_t)l * DIM + og * 16) * LORA;
  for (int i = tid; i < 16 * LORA; i += 256) Bs[i] = Bbase[i];
#pragma unroll
  for (int i = 0; i < 5; ++i) {            // stage A rows 0..9
    const int f4 = i * 256 + tid;
    ((float4*)As)[f4] = *(const float4*)(Abase + (size_t)(f4 >> 7) * DIM + (f4 & 127) * 4);
  }
  __syncthreads();

  const int tc = tid & 31;                 // col quad: c = v*128 + tc*4
  const int tr = tid >> 5;                 // 8 row-pairs

  float acc[2][16];                        // 32 VGPR
  size_t rowb[2];
#pragma unroll
  for (int u = 0; u < 2; ++u) {
    const int orow = og * 16 + tr * 2 + u;
    rowb[u] = ((size_t)l * DIM + orow) * DIM + cg * 512;
    const size_t scb = ((size_t)l * DIM + orow) * (DIM / GROUP) + cg * 32;
#pragma unroll
    for (int v = 0; v < 4; ++v) {
      const int c = v * 128 + tc * 4;
      const int4 q4 = *(const int4*)&qw[rowb[u] + c];
      const float sv = sc[scb + (c >> 4)];
      acc[u][v * 4 + 0] = q4.x * sv;
      acc[u][v * 4 + 1] = q4.y * sv;
      acc[u][v * 4 + 2] = q4.z * sv;
      acc[u][v * 4 + 3] = q4.w * sv;
    }
  }

#pragma unroll 1
  for (int half = 0; half < 2; ++half) {
    if (half == 1) {
      __syncthreads();
#pragma unroll
      for (int i = 0; i < 5; ++i) {        // stage A rows 10..19
        const int f4 = i * 256 + tid;
        ((float4*)As)[f4] =
            *(const float4*)(Abase + (size_t)(10 + (f4 >> 7)) * DIM + (f4 & 127) * 4);
      }
      __syncthreads();
    }
#pragma unroll 2
    for (int jj = 0; jj < 10; ++jj) {
      const int j = half * 10 + jj;
      float4 a[4];
#pragma unroll
      for (int v = 0; v < 4; ++v)
        a[v] = *(const float4*)&As[jj * 512 + v * 128 + tc * 4];
#pragma unroll
      for (int u = 0; u < 2; ++u) {
        const float bj = Bs[(tr * 2 + u) * LORA + j];
#pragma unroll
        for (int v = 0; v < 4; ++v) {
          acc[u][v * 4 + 0] += bj * a[v].x;
          acc[u][v * 4 + 1] += bj * a[v].y;
          acc[u][v * 4 + 2] += bj * a[v].z;
          acc[u][v * 4 + 3] += bj * a[v].w;
        }
      }
    }
  }

#pragma unroll
  for (int u = 0; u < 2; ++u) {
#pragma unroll
    for (int v = 0; v < 4; ++v) {
      const bf16_4 hv = {(__bf16)acc[u][v * 4 + 0], (__bf16)acc[u][v * 4 + 1],
                         (__bf16)acc[u][v * 4 + 2], (__bf16)acc[u][v * 4 + 3]};
      *(bf16_4*)&whi[rowb[u] + v * 128 + tc * 4] = hv;
    }
  }
}

// ---------------------------------------------------------------------------
// x prep: f32 -> single bf16
// ---------------------------------------------------------------------------
__global__ __launch_bounds__(256) void xprep_kernel(
    const float* __restrict__ x, __bf16* __restrict__ hi) {
  const size_t i = (size_t)blockIdx.x * 256 + threadIdx.x;
  const float4 v = ((const float4*)x)[i];
  const bf16_4 hv = {(__bf16)v.x, (__bf16)v.y, (__bf16)v.z, (__bf16)v.w};
  ((bf16_4*)hi)[i] = hv;
}

// ---------------------------------------------------------------------------
// 1-pass bf16 GEMM.  Tile 256x128, BK=32, 512 thr (8 waves: 4 batch x 2 feat),
// 3 x 24KB LDS buffers (X 16KB | W 8KB), counted vmcnt(3) (1 tile in flight),
// grid 256 = 1 block/CU.  LDS flow/K-step/CU: 64KB read + 24KB write (was
// 96+32 at 2-pass) -> ~0.69x dispatch time.
// ---------------------------------------------------------------------------
#define GBUF    12288   // elems per buffer (24 KB)
#define GOFF_W  8192    // X 256x32 elems first, then W 128x32

template <int NISSUE>
__device__ __forceinline__ void stageR(const __bf16* __restrict__ g, int row0, int k0,
                                       __bf16* lds, int tid) {
#pragma unroll
  for (int i = 0; i < NISSUE; ++i) {
    const int D = i * 8192 + tid * 16;     // linear byte in region
    const int r  = D >> 6;                 // 64 B per row (BK=32 bf16)
    const int ce = (D & 63) >> 1;
    const __bf16* gp = g + (size_t)(row0 + r) * DIM + k0 + ce;
    __builtin_amdgcn_global_load_lds(
        (const __attribute__((address_space(1))) void*)gp,
        (__attribute__((address_space(3))) void*)(lds + i * 4096 + (tid >> 6) * 512), 16, 0, 0);
  }
}

template <bool RELU_OUT>
__global__ __launch_bounds__(512, 1) void gemm1_kernel(
    const __bf16* __restrict__ X, const __bf16* __restrict__ Wh,
    const float* __restrict__ bias, __bf16* __restrict__ Oh,
    const float* __restrict__ Hin, float* __restrict__ Sout) {
  __shared__ __bf16 smem[3 * GBUF];        // 72 KB

  const int tid  = threadIdx.x;
  const int lane = tid & 63;
  const int wv   = tid >> 6;
  const int wm   = wv >> 2;                // feature half (2 x 64)
  const int wn2  = wv & 3;                 // batch quarter (4 x 64)
  const int xcd = blockIdx.x & 7;
  const int kk  = blockIdx.x >> 3;         // 0..31
  const int tm  = xcd * 4 + (kk >> 3);
  const int tn  = kk & 7;
  const int rowX = tm * 256, rowW = tn * 128;

  const int lr   = lane & 15;
  const int slot = lane >> 4;

  int offX[4], offW[4];
#pragma unroll
  for (int n = 0; n < 4; ++n) offX[n] = (wn2 * 64 + n * 16 + lr) * 32 + slot * 8;
#pragma unroll
  for (int m = 0; m < 4; ++m) offW[m] = GOFF_W + (wm * 64 + m * 16 + lr) * 32 + slot * 8;

  f32x4 acc[4][4];
#pragma unroll
  for (int m = 0; m < 4; ++m)
#pragma unroll
    for (int n = 0; n < 4; ++n) acc[m][n] = f32x4{0.f, 0.f, 0.f, 0.f};

  auto stage_tile = [&](int k0, __bf16* sb) {
    stageR<2>(X,  rowX, k0, sb, tid);
    stageR<1>(Wh, rowW, k0, sb + GOFF_W, tid);
  };

  auto compute_tile = [&](const __bf16* buf) {
    bf16_8 xf[4];
#pragma unroll
    for (int n = 0; n < 4; ++n) xf[n] = *(const bf16_8*)&buf[offX[n]];
#pragma unroll
    for (int m = 0; m < 4; ++m) {
      const bf16_8 w_h = *(const bf16_8*)&buf[offW[m]];
#pragma unroll
      for (int n = 0; n < 4; ++n)
        acc[m][n] = __builtin_amdgcn_mfma_f32_16x16x32_bf16(w_h, xf[n], acc[m][n], 0, 0, 0);
    }
  };

  stage_tile(0, smem);
  stage_tile(32, smem + GBUF);
  asm volatile("s_waitcnt vmcnt(3)" ::: "memory");   // tile 0 landed
  __builtin_amdgcn_s_barrier();

  int cur = 0;
#pragma unroll 1
  for (int kt = 0; kt < 30; ++kt) {
    int pb = cur + 2; if (pb >= 3) pb -= 3;
    stage_tile((kt + 2) * 32, smem + pb * GBUF);
    compute_tile(smem + cur * GBUF);
    // drain tile kt+1's 3 loads (oldest); kt+2's 3 newest stay in flight
    asm volatile("s_waitcnt vmcnt(3)" ::: "memory");
    __builtin_amdgcn_s_barrier();
    ++cur; if (cur == 3) cur = 0;
  }
  compute_tile(smem + cur * GBUF);
  asm volatile("s_waitcnt vmcnt(0)" ::: "memory");
  __builtin_amdgcn_s_barrier();
  ++cur; if (cur == 3) cur = 0;
  compute_tile(smem + cur * GBUF);

  const int g4 = slot * 4;
#pragma unroll
  for (int m = 0; m < 4; ++m) {
    const int feat = tn * 128 + wm * 64 + m * 16 + g4;
    const float4 bv = *(const float4*)&bias[feat];
#pragma unroll
    for (int n = 0; n < 4; ++n) {
      const int nb = tm * 256 + wn2 * 64 + n * 16 + lr;
      const size_t base = (size_t)nb * DIM + feat;
      float v0 = acc[m][n][0] + bv.x;
      float v1 = acc[m][n][1] + bv.y;
      float v2 = acc[m][n][2] + bv.z;
      float v3 = acc[m][n][3] + bv.w;
      if constexpr (RELU_OUT) {
        const bf16_4 hv = {(__bf16)fmaxf(v0, 0.f), (__bf16)fmaxf(v1, 0.f),
                           (__bf16)fmaxf(v2, 0.f), (__bf16)fmaxf(v3, 0.f)};
        *(bf16_4*)&Oh[base] = hv;
      } else {
        const float4 h = *(const float4*)&Hin[base];
        *(float4*)&Sout[base] = float4{v0 + h.x, v1 + h.y, v2 + h.z, v3 + h.w};
      }
    }
  }
}

// ---------------------------------------------------------------------------
// Row LayerNorm: H = LN(S)*w+b (f32) plus bf16 cast (next block's GEMM input).
// ---------------------------------------------------------------------------
__global__ __launch_bounds__(256) void ln_kernel(
    const float* __restrict__ S, const float* __restrict__ w,
    const float* __restrict__ b, float* __restrict__ H,
    __bf16* __restrict__ phi) {
  const int row = blockIdx.x;
  const int tid = threadIdx.x;
  const int lane = tid & 63;
  const int wv = tid >> 6;
  const float4 v = ((const float4*)(S + (size_t)row * DIM))[tid];

  float s = v.x + v.y + v.z + v.w;
#pragma unroll
  for (int m = 32; m; m >>= 1) s += __shfl_xor(s, m, 64);
  __shared__ float red[8];
  if (lane == 0) red[wv] = s;
  __syncthreads();
  const float mean = (red[0] + red[1] + red[2] + red[3]) * (1.f / DIM);

  const float d0 = v.x - mean, d1 = v.y - mean, d2 = v.z - mean, d3 = v.w - mean;
  float q = d0 * d0 + d1 * d1 + d2 * d2 + d3 * d3;
#pragma unroll
  for (int m = 32; m; m >>= 1) q += __shfl_xor(q, m, 64);
  if (lane == 0) red[4 + wv] = q;
  __syncthreads();
  const float var = (red[4] + red[5] + red[6] + red[7]) * (1.f / DIM);
  const float inv = 1.f / sqrtf(var + EPS);

  const float4 wv4 = ((const float4*)w)[tid];
  const float4 bv4 = ((const float4*)b)[tid];
  const float y0 = d0 * inv * wv4.x + bv4.x;
  const float y1 = d1 * inv * wv4.y + bv4.y;
  const float y2 = d2 * inv * wv4.z + bv4.z;
  const float y3 = d3 * inv * wv4.w + bv4.w;

  ((float4*)(H + (size_t)row * DIM))[tid] = float4{y0, y1, y2, y3};
  const bf16_4 hv = {(__bf16)y0, (__bf16)y1, (__bf16)y2, (__bf16)y3};
  ((bf16_4*)phi)[(size_t)row * (DIM / 4) + tid] = hv;
}

// ---------------------------------------------------------------------------
// launch
// ---------------------------------------------------------------------------
extern "C" void kernel_launch(void* const* d_in, const int* in_sizes, int n_in,
                              void* d_out, int out_size, void* d_ws, size_t ws_size,
                              hipStream_t stream) {
  const float* x   = (const float*)d_in[0];
  const int*   qw  = (const int*)d_in[1];
  const float* sc  = (const float*)d_in[2];
  const float* bias= (const float*)d_in[3];
  const float* la  = (const float*)d_in[4];
  const float* lb  = (const float*)d_in[5];
  const float* lnw = (const float*)d_in[6];
  const float* lnb = (const float*)d_in[7];
  float* out = (float*)d_out;
  char* ws = (char*)d_ws;

  // workspace layout (bytes): WHI 36M | X0 16M | X1 16M | Sb 32M | Hb 32M
  __bf16* WHI = (__bf16*)(ws);
  __bf16* X0  = (__bf16*)(ws + 37748736);
  __bf16* X1  = (__bf16*)(ws + 54525952);
  float*  Sb  = (float*)(ws + 71303168);
  float*  Hb  = (float*)(ws + 104857600);
  (void)ws_size; (void)in_sizes; (void)n_in; (void)out_size;

  xprep_kernel<<<BATCH * DIM / (256 * 4), 256, 0, stream>>>(x, X0);
  wprep_kernel<<<NLAYERS * 128, 256, 0, stream>>>(qw, sc, la, lb, WHI);

  const dim3 ggrid(BATCH / 256 * (DIM / 128));  // 32 * 8 = 256 = 1 block/CU
  for (int blk = 0; blk < NBLOCKS; ++blk) {
    const int li = blk * 3;
    const size_t w0 = (size_t)li * DIM * DIM;
    const size_t w1 = (size_t)(li + 1) * DIM * DIM;
    const size_t w2 = (size_t)(li + 2) * DIM * DIM;

    gemm1_kernel<true><<<ggrid, 512, 0, stream>>>(
        X0, WHI + w0, bias + (size_t)li * DIM, X1, nullptr, nullptr);
    gemm1_kernel<true><<<ggrid, 512, 0, stream>>>(
        X1, WHI + w1, bias + (size_t)(li + 1) * DIM, X0, nullptr, nullptr);
    const float* hin = (blk == 0) ? x : Hb;
    float* sout = (blk == NBLOCKS - 1) ? out : Sb;
    gemm1_kernel<false><<<ggrid, 512, 0, stream>>>(
        X0, WHI + w2, bias + (size_t)(li + 2) * DIM, nullptr, hin, sout);
    if (blk < NBLOCKS - 1) {
      ln_kernel<<<BATCH, 256, 0, stream>>>(Sb, lnw + (size_t)blk * DIM,
                                           lnb + (size_t)blk * DIM, Hb, X0);
    }
  }
}